// Round 8
// baseline (300.772 us; speedup 1.0000x reference)
//
#include <hip/hip_runtime.h>

// Problem: B=32,T=12,N=325,D=64,H=4,HD=16,M_SP=32,M_T=6, SCALE=0.25
// Inputs fp32 (+ int32 mode lists); output fp32.
//
// Key identities used:
//  * temporal branch: softmax axis == mean axis  =>  out = vf/6. Whole branch is
//    v=x@Wv_t^T (fake (n',t') reshape r = n'*12+t'), drop Nyquist of 12-pt rfft, /6.
//    te = (vt - sgn*alt/12)/6 = ((x_s - sgn*xa_n/12)/6) @ Wvt^T  (linearity);
//    xa[b,n'] = sum_s (-1)^s x[b, n'*12+s]. VT (32MB) never materialized.
//  * rfft over n commutes with channel linear => one DFT of x, then 64x64 matmuls.
//  * GCN: Wc = W_mlp @ W_fc1 folded; out = A_rownorm @ (x @ Wc^T) + b.
//
// R15 (this round): norm pass folded into mega with in-kernel flag sync.
//  - R14 accounting: top-5 all mega => prep<55, final2<55; ~65-75us lives in
//    serial prep + kernel boundaries. Remove the serial stage:
//  - mega blocks 0..974 = norm pass (bucketed atomicAdd + threadfence + arrival
//    counter). Spatial blocks spin at START of phase C (after all their GEMMs)
//    until counter==975, then read buckets via device-scope atomic reads.
//  - DEADLOCK-FREE BY COUNTING: 384 spatial blocks < 768 resident slots
//    (51.2KB LDS -> 3 blocks/CU x 256 CU), so >=384 slots always free for norm
//    blocks regardless of dispatch order; norm blocks wait on nothing.
//  - prep shrinks to 22 blocks (Wc, |wQ|, TB/T2, WSPB). Memset zeroes buckets
//    + counter (513 floats).

typedef unsigned short u16;
typedef short short8 __attribute__((ext_vector_type(8)));
typedef float floatx4 __attribute__((ext_vector_type(4)));

__device__ __forceinline__ u16 f2bf(float f) {
  union { float fp; unsigned int u; } v; v.fp = f;
  unsigned int x = v.u;
  x += 0x7FFF + ((x >> 16) & 1);   // RNE
  return (u16)(x >> 16);
}

// ---- workspace layout (float offsets; u16 arrays count as size/2 floats) ----
constexpr size_t OFF_NORM = 4096;       // 16 buckets x 32 floats (128B stride);
                                        // bucket k: [32k]=sum q^2, [32k+1]=sum k^2
                                        // [4096+512] = arrival counter (u32)
constexpr size_t OFF_WQA  = 8208;       // 15872   |weights_Q|
constexpr size_t OFF_ANB  = 24080;      // u16[325*352]   row-norm adj, bf16, col-pad 352
constexpr size_t OFF_TB   = 81280;      // u16[64*352]    DFT matrix bf16, rows interleaved re/im
constexpr size_t OFF_T2   = 102080;     // u16[325*64]    irfft: [n][2j]=wc_j cos, [n][2j+1]=-wc_j sin
constexpr size_t OFF_OFT  = 112480;     // u16[384*64*64] spectrum [bt][d][2j|2j+1] (re,im)
constexpr size_t OFF_XCT  = 898912;     // u16[384*64*352] xc transposed [bt][d][n], n-pad 352
// weight tables live in the freed VT region (no aliasing with XA)
constexpr size_t OFF_WBB  = 5224288;    // u16[64*64]   Wc bf16 (mega/linear2 B)
constexpr size_t OFF_WSPB = 5226336;    // u16[192*64]  [Wq|Wk|Wv] bf16 (spatial B)
constexpr size_t OFF_WVTB = 5232480;    // u16[64*64]   Wvt bf16 (k_final2 te GEMM)
constexpr size_t OFF_XA   = 13211488;   // f32[32*325*64]  alternating x sums

// ===========  K1 (R15, tiny): weights bf16, |wQ|, twiddles  ===========
__global__ __launch_bounds__(256) void k_prep(const float* __restrict__ Wmlp,
                                              const float* __restrict__ Wfc1,
                                              const float* __restrict__ wQ,
                                              const float* __restrict__ Wq,
                                              const float* __restrict__ Wk,
                                              const float* __restrict__ Wv,
                                              const int* __restrict__ sp_modes,
                                              float* __restrict__ ws) {
  const int tid = threadIdx.x;
  const int blk = blockIdx.x;
  u16* WBBu = (u16*)(ws + OFF_WBB);
  if (blk == 0) {
    // Wc = Wmlp @ Wfc1, straight to bf16
    for (int o = tid; o < 4096; o += 256) {
      int g = o >> 6, dd = o & 63;
      float s = 0.f;
      for (int e = 0; e < 64; ++e)
        s = fmaf(Wmlp[g * 64 + e], Wfc1[e * 64 + dd], s);
      WBBu[o] = f2bf(s);
    }
  } else if (blk < 9) {
    for (int i = (blk - 1) * 256 + tid; i < 15872; i += 2048)
      ws[OFF_WQA + i] = fabsf(wQ[i]);
  } else if (blk < 21) {
    const int j = blk - 9;
    // 12 blocks, each handles modes j, j+12, j+24
    u16* T2B = (u16*)(ws + OFF_T2);
    u16* TB = (u16*)(ws + OFF_TB);
    for (int jj = j; jj < 32; jj += 12) {
      const int f = sp_modes[jj];
      const float wgt = (f == 0) ? 1.f : 2.f;
      const int row_re = 8 * (jj >> 2) + (jj & 3);
      const int row_im = row_re + 4;
      for (int n = tid; n < 352; n += 256) {
        float c = 0.f, s = 0.f;
        if (n < 325) {
          int mm = (f * n) % 325;               // exact range reduction
          float th = 6.283185307179586f * (float)mm * (1.f / 325.f);
          c = cosf(th);
          s = sinf(th);
        }
        TB[(size_t)row_re * 352 + n] = f2bf(c);
        TB[(size_t)row_im * 352 + n] = f2bf(-s);
        if (n < 325) {
          T2B[(size_t)n * 64 + 2 * jj] = f2bf(wgt * (1.f / 325.f) * c);
          T2B[(size_t)n * 64 + 2 * jj + 1] = f2bf(-wgt * (1.f / 325.f) * s);
        }
      }
    }
  } else {  // blk == 21
    u16* WSPBu = (u16*)(ws + OFF_WSPB);
    for (int i = tid; i < 12288; i += 256) {
      const int r = i >> 6, e = i & 63;
      const float* src = (r < 64) ? Wq : (r < 128) ? Wk : Wv;
      WSPBu[i] = f2bf(src[(size_t)(r & 63) * 64 + e]);
    }
  }
}

// ===========  K2 (R15): MEGA — norm|spatial|linear2|xa|ANB|pads|WVTB  ===========
__global__ __launch_bounds__(256) void k_mega(const float* __restrict__ x,
                                              const float* __restrict__ adj,
                                              const float* __restrict__ Wq,
                                              const float* __restrict__ Wk,
                                              const float* __restrict__ Wvt,
                                              float* __restrict__ ws) {
  __shared__ __align__(16) float smem[12800];   // 51,200 B (spatial worst case)
  const int tid = threadIdx.x;
  const int blk = blockIdx.x;
  const int lane = tid & 63, wv = tid >> 6;
  const int lc = lane & 15, quad = lane >> 4;

  if (blk < 975) {
    // ========== norm: partial ||q||^2,||k||^2 over 128 x-rows -> buckets+counter ==========
    u16* XAu = (u16*)smem;                 // [128][72] u16 = 18,432 B
    float* red = smem + 4608;              // 16 floats past XA
    const size_t base = (size_t)blk * 128;
    for (int i = tid; i < 2048; i += 256) {
      const int row = i >> 4, e0 = (i & 15) * 4;
      const float4 v = *(const float4*)(x + (base + row) * 64 + e0);
      u16* dst = &XAu[row * 72 + e0];
      dst[0] = f2bf(v.x); dst[1] = f2bf(v.y); dst[2] = f2bf(v.z); dst[3] = f2bf(v.w);
    }
    __syncthreads();
    floatx4 acc[2][8] = {};
#pragma unroll
    for (int kc = 0; kc < 2; ++kc) {
      short8 af[2];
#pragma unroll
      for (int mi = 0; mi < 2; ++mi)
        af[mi] = *(const short8*)&XAu[(32 * wv + 16 * mi + lc) * 72 + kc * 32 + quad * 8];
#pragma unroll
      for (int ni = 0; ni < 8; ++ni) {
        const int g = (ni & 3) * 16 + lc;
        const float* src = ((ni < 4) ? Wq : Wk) + (size_t)g * 64 + kc * 32 + quad * 8;
        float v8[8];
        *(float4*)v8 = *(const float4*)src;
        *(float4*)(v8 + 4) = *(const float4*)(src + 4);
        short8 bf_;
#pragma unroll
        for (int u = 0; u < 8; ++u) bf_[u] = (short)f2bf(v8[u]);
#pragma unroll
        for (int mi = 0; mi < 2; ++mi)
          acc[mi][ni] = __builtin_amdgcn_mfma_f32_16x16x32_bf16(af[mi], bf_, acc[mi][ni], 0, 0, 0);
      }
    }
    float sq = 0.f, sk = 0.f;
#pragma unroll
    for (int mi = 0; mi < 2; ++mi)
#pragma unroll
      for (int reg = 0; reg < 4; ++reg) {
#pragma unroll
        for (int ni = 0; ni < 4; ++ni) {
          const float v = acc[mi][ni][reg];
          sq = fmaf(v, v, sq);
        }
#pragma unroll
        for (int ni = 4; ni < 8; ++ni) {
          const float v = acc[mi][ni][reg];
          sk = fmaf(v, v, sk);
        }
      }
    for (int off = 32; off > 0; off >>= 1) {
      sq += __shfl_down(sq, off);
      sk += __shfl_down(sk, off);
    }
    if (lane == 0) { red[wv] = sq; red[8 + wv] = sk; }
    __syncthreads();
    if (tid == 0) {
      const size_t bucket = OFF_NORM + 32 * (size_t)(blk & 15);
      atomicAdd(&ws[bucket + 0], red[0] + red[1] + red[2] + red[3]);
      atomicAdd(&ws[bucket + 1], red[8] + red[9] + red[10] + red[11]);
      __threadfence();
      atomicAdd((unsigned int*)&ws[OFF_NORM + 512], 1u);
    }
  } else if (blk < 1359) {
    // ================= spatial branch per bt =================
    const int bt = blk - 975;
    u16* XBu = (u16*)smem;                       // [64 e][360 n]

    const u16* TB = (const u16*)(ws + OFF_TB);
    const u16* WSPBu = (const u16*)(ws + OFF_WSPB);
    const float* xb = x + (size_t)bt * 20800;
    const int br = tid & 31, be0 = (tid >> 5) * 8;

    // ---- stage whole x-tile -> XB (bf16, [e][n]) ----
    {
      float va[4][8];
#pragma unroll
      for (int g = 0; g < 3; ++g) {
        const int nkc = (g < 2) ? 4 : 3;
#pragma unroll
        for (int u = 0; u < 4; ++u) {
          if (u >= nkc) break;
          const int k0 = (g * 4 + u) * 32;
          if (k0 + br < 325) {
            const float* src = xb + (size_t)(k0 + br) * 64 + be0;
            *(float4*)&va[u][0] = *(const float4*)src;
            *(float4*)&va[u][4] = *(const float4*)(src + 4);
          } else {
#pragma unroll
            for (int w = 0; w < 8; ++w) va[u][w] = 0.f;
          }
        }
#pragma unroll
        for (int u = 0; u < 4; ++u) {
          if (u >= nkc) break;
          const int k0 = (g * 4 + u) * 32;
#pragma unroll
          for (int w = 0; w < 8; ++w)
            XBu[(be0 + w) * 360 + k0 + br] = f2bf(va[u][w]);
        }
      }
    }
    __syncthreads();

    // ---- Phase A: DFT GEMM, barrier-free ----
    floatx4 accA[4] = {};
#pragma unroll
    for (int kc = 0; kc < 11; ++kc) {
      const short8 af = *(const short8*)&TB[(size_t)(16 * wv + lc) * 352 + kc * 32 + quad * 8];
#pragma unroll
      for (int t = 0; t < 4; ++t) {
        const short8 bf_ = *(const short8*)&XBu[(t * 16 + lc) * 360 + kc * 32 + quad * 8];
        accA[t] = __builtin_amdgcn_mfma_f32_16x16x32_bf16(af, bf_, accA[t], 0, 0, 0);
      }
    }
    __syncthreads();   // all XB reads done; first 10,240B reused as xfl2

    u16* xfl2 = XBu;
#pragma unroll
    for (int t = 0; t < 4; ++t)
#pragma unroll
      for (int r = 0; r < 4; ++r)
        xfl2[(t >> 1) * 2560 + (16 * wv + quad * 4 + r) * 40 + (t & 1) * 16 + lc] =
            f2bf(accA[t][r]);
    __syncthreads();

    // ---- Phase B: projection GEMM ----
    floatx4 acc2[12] = {};
#pragma unroll
    for (int kc2 = 0; kc2 < 2; ++kc2) {
      const short8 af2 = *(const short8*)&xfl2[kc2 * 2560 + (16 * wv + lc) * 40 + quad * 8];
#pragma unroll
      for (int t = 0; t < 12; ++t) {
        const short8 bf2 = *(const short8*)&WSPBu[(t * 16 + lc) * 64 + kc2 * 32 + quad * 8];
        acc2[t] = __builtin_amdgcn_mfma_f32_16x16x32_bf16(af2, bf2, acc2[t], 0, 0, 0);
      }
    }
    __syncthreads();   // xfl2 dead past here; smem[0..1] reusable

    // ---- Phase C ----
    float* sq_q = smem + 2560;      // [32][64]
    float* sq_k = smem + 4608;      // [32][64] -> absk*SCALE/||k||
    float* vfre = smem + 6656;
    float* vfim = smem + 8704;
    float* wbar = smem + 10752;
    for (int i = tid; i < 2048; i += 256) wbar[i] = 0.f;
    {
      const int fb = 8 * wv + ((quad >= 2) ? 4 : 0);
      const int isim = quad & 1;
#pragma unroll
      for (int t = 0; t < 12; ++t) {
        const int mat = t >> 2;
        const int d = (t & 3) * 16 + lc;
#pragma unroll
        for (int r = 0; r < 4; ++r) {
          const float v = acc2[t][r];
          if (mat == 2) {
            if (isim) vfim[(fb + r) * 64 + d] = v;
            else vfre[(fb + r) * 64 + d] = v;
          } else {
            const float s2 = v * v + __shfl_xor(v * v, 16);
            if (!isim) {
              if (mat == 0) sq_q[(fb + r) * 64 + d] = s2;
              else sq_k[(fb + r) * 64 + d] = s2;
            }
          }
        }
      }
    }
    // ---- norm spin: wait for all 975 norm blocks, then read buckets ----
    // Deadlock-free: 384 spatial blocks < 768 resident slots => norm blocks
    // always have slots to run; they wait on nothing.
    if (tid == 0) {
      unsigned c;
      do {
        c = atomicAdd((unsigned int*)&ws[OFF_NORM + 512], 0u);
        if (c < 975u) __builtin_amdgcn_s_sleep(10);
      } while (c < 975u);
      float nq = 0.f, nk = 0.f;
      for (int k2 = 0; k2 < 16; ++k2) {
        nq += atomicAdd(&ws[OFF_NORM + 32 * (size_t)k2 + 0], 0.f);
        nk += atomicAdd(&ws[OFF_NORM + 32 * (size_t)k2 + 1], 0.f);
      }
      smem[0] = nq; smem[1] = nk;
    }
    __syncthreads();
    const float inv_nq = rsqrtf(smem[0]);
    const float inv_nk = rsqrtf(smem[1]);
    for (int i = tid; i < 2048; i += 256)
      sq_k[i] = 0.25f * inv_nk * sqrtf(sq_k[i]);
    __syncthreads();
    {
      const int d = tid & 63, fb2 = tid >> 6, hd = d & 15;
      const float* wqa = ws + OFF_WQA;
      float wacc[32];
#pragma unroll
      for (int j = 0; j < 32; ++j) wacc[j] = 0.f;
      for (int r8 = 0; r8 < 8; ++r8) {
        const int m = fb2 + (r8 << 2);
        const float aq = inv_nq * sqrtf(sq_q[m * 64 + d]);
        float sv[32];
        float mx = -1e30f;
#pragma unroll
        for (int j = 0; j < 32; ++j) {
          const float a = (j == 0) ? aq : wqa[(m * 31 + (j - 1)) * 16 + hd];
          const float s = sq_k[j * 64 + d] * a;
          sv[j] = s;
          mx = fmaxf(mx, s);
        }
        float sum = 0.f;
#pragma unroll
        for (int j = 0; j < 32; ++j) {
          const float ev = __expf(sv[j] - mx);
          sv[j] = ev;
          sum += ev;
        }
        const float sc = 0.03125f / sum;
#pragma unroll
        for (int j = 0; j < 32; ++j) wacc[j] += sv[j] * sc;
      }
#pragma unroll
      for (int j = 0; j < 32; ++j) atomicAdd(&wbar[j * 64 + d], wacc[j]);
    }
    __syncthreads();
    unsigned int* OFTu = (unsigned int*)(ws + OFF_OFT) + (size_t)bt * 2048;
    for (int i2 = tid; i2 < 2048; i2 += 256) {
      const int d = i2 >> 5, j = i2 & 31;
      const float w = wbar[j * 64 + d];
      const unsigned int lo = f2bf(vfre[j * 64 + d] * w);
      const unsigned int hi = f2bf(vfim[j * 64 + d] * w);
      OFTu[i2] = lo | (hi << 16);
    }
  } else if (blk < 2334) {
    // ================= linear2 (Wc only): xc -> XCT =================
    const int blk2 = blk - 1359;
    u16* XAu = (u16*)smem;                 // [128][72] u16; reused as xcT[64][132]
    const size_t base = (size_t)blk2 * 128;
    const u16* WBBu = (const u16*)(ws + OFF_WBB);

    for (int i = tid; i < 2048; i += 256) {
      const int row = i >> 4, e0 = (i & 15) * 4;
      const float4 v = *(const float4*)(x + (base + row) * 64 + e0);
      u16* dst = &XAu[row * 72 + e0];
      dst[0] = f2bf(v.x); dst[1] = f2bf(v.y); dst[2] = f2bf(v.z); dst[3] = f2bf(v.w);
    }
    __syncthreads();

    floatx4 acc[2][4] = {};
#pragma unroll
    for (int kc = 0; kc < 2; ++kc) {
      short8 af[2];
#pragma unroll
      for (int mi = 0; mi < 2; ++mi)
        af[mi] = *(const short8*)&XAu[(32 * wv + 16 * mi + lc) * 72 + kc * 32 + quad * 8];
#pragma unroll
      for (int ni = 0; ni < 4; ++ni) {
        const short8 bf_ = *(const short8*)&WBBu[(ni * 16 + lc) * 64 + kc * 32 + quad * 8];
#pragma unroll
        for (int mi = 0; mi < 2; ++mi)
          acc[mi][ni] = __builtin_amdgcn_mfma_f32_16x16x32_bf16(af[mi], bf_, acc[mi][ni], 0, 0, 0);
      }
    }
    __syncthreads();   // all XA reads complete before xcT overwrite

    u16* xcT = XAu;    // [64 d][132]
#pragma unroll
    for (int ni = 0; ni < 4; ++ni)
#pragma unroll
      for (int mi = 0; mi < 2; ++mi)
#pragma unroll
        for (int reg = 0; reg < 4; ++reg)
          xcT[(ni * 16 + lc) * 132 + 32 * wv + 16 * mi + quad * 4 + reg] =
              f2bf(acc[mi][ni][reg]);
    __syncthreads();
    u16* XCT = (u16*)(ws + OFF_XCT);
    for (int i = tid; i < 8192; i += 256) {
      const int d = i >> 7, r = i & 127;
      const unsigned int row = (unsigned int)(base + r);
      const unsigned int bt = row / 325u;
      const unsigned int n = row - bt * 325u;
      XCT[(size_t)bt * 22528 + (size_t)d * 352 + n] = xcT[d * 132 + r];
    }
  } else if (blk < 2984) {
    // ================= xa: alternating sums of x =================
    const int idx = (blk - 2334) * 256 + tid;
    if (idx >= 32 * 325 * 16) return;
    const int dq = idx & 15;            // float4 slot
    const int n = (idx >> 4) % 325;
    const int b = idx / (16 * 325);
    const float* xp = x + ((size_t)b * 3900 + (size_t)n * 12) * 64 + dq * 4;
    float4 s = make_float4(0.f, 0.f, 0.f, 0.f);
    float sign = 1.f;
    for (int k = 0; k < 12; ++k) {
      const float4 v = *(const float4*)(xp + (size_t)k * 64);
      s.x += sign * v.x; s.y += sign * v.y; s.z += sign * v.z; s.w += sign * v.w;
      sign = -sign;
    }
    *(float4*)(ws + OFF_XA + ((size_t)b * 325 + n) * 64 + dq * 4) = s;
  } else if (blk < 3309) {
    // ================= ANB: adj row-normalize -> bf16 (final2-only) =================
    const int n = blk - 2984;           // < 325
    float* red = smem;
    float p = 0.f;
    for (int k = tid; k < 325; k += 256) p += adj[n * 325 + k];
    red[tid] = p;
    __syncthreads();
    for (int s2 = 128; s2 > 0; s2 >>= 1) {
      if (tid < s2) red[tid] += red[tid + s2];
      __syncthreads();
    }
    const float inv = 1.f / red[0];
    u16* ANB = (u16*)(ws + OFF_ANB);
    for (int k = tid; k < 352; k += 256)
      ANB[(size_t)n * 352 + k] = (k < 325) ? f2bf(adj[n * 325 + k] * inv) : (u16)0;
  } else if (blk < 3405) {
    // ================= XCT n-pad zeroing (final2-only) =================
    const int idx = (blk - 3309) * 256 + tid;   // < 24576 = 384*64
    u16* p = (u16*)(ws + OFF_XCT) + (size_t)(idx >> 6) * 22528 + (size_t)(idx & 63) * 352;
    for (int c = 325; c < 352; ++c) p[c] = 0;
  } else {
    // ================= WVTB (final2-only) =================
    u16* WVTBu = (u16*)(ws + OFF_WVTB);
    for (int i = tid; i < 4096; i += 256) WVTBu[i] = f2bf(Wvt[i]);
  }
}

// =======  K3: barrier-free MFMA — C = AN@XCT + T2@OFT + TE@Wvt + bias  =======
__global__ __launch_bounds__(256) void k_final2(const float* __restrict__ x,
                                                const float* __restrict__ bmlp,
                                                float* __restrict__ ws,
                                                float* __restrict__ out) {
  const int tid = threadIdx.x;
  const int bt = blockIdx.x / 3, mc = blockIdx.x % 3;
  const int m0 = mc * 128;
  const int wave = tid >> 6, lane = tid & 63;
  const int quad = lane >> 4, lc = lane & 15;

  const u16* ANB = (const u16*)(ws + OFF_ANB);
  const u16* T2B = (const u16*)(ws + OFF_T2);
  const u16* XCT = (const u16*)(ws + OFF_XCT) + (size_t)bt * 22528;
  const u16* OFT = (const u16*)(ws + OFF_OFT) + (size_t)bt * 4096;
  const u16* WVTBu = (const u16*)(ws + OFF_WVTB);

  const int b = bt / 12, t = bt - b * 12;
  const float sgn12 = ((t & 1) ? -1.f : 1.f) * (1.f / 12.f);

  floatx4 acc[2][4] = {};

#pragma unroll
  for (int c13 = 0; c13 < 13; ++c13) {
    const bool gcn = (c13 < 11);
    const u16* Asrc = gcn ? ANB : T2B;
    const int astr = gcn ? 352 : 64;
    const int acol = gcn ? c13 * 32 : (c13 - 11) * 32;
    const u16* Bsrc = gcn ? XCT : OFT;
    const int bstr = gcn ? 352 : 64;
    short8 af[2], bf_[4];
#pragma unroll
    for (int mi = 0; mi < 2; ++mi) {
      const int gr = m0 + wave * 32 + mi * 16 + lc;
      short8 a = {};
      if (gr < 325)
        a = *(const short8*)&Asrc[(size_t)gr * astr + acol + quad * 8];
      af[mi] = a;
    }
#pragma unroll
    for (int ni = 0; ni < 4; ++ni)
      bf_[ni] = *(const short8*)&Bsrc[(size_t)(ni * 16 + lc) * bstr + acol + quad * 8];
#pragma unroll
    for (int mi = 0; mi < 2; ++mi)
#pragma unroll
      for (int ni = 0; ni < 4; ++ni)
        acc[mi][ni] = __builtin_amdgcn_mfma_f32_16x16x32_bf16(
            af[mi], bf_[ni], acc[mi][ni], 0, 0, 0);
  }

  // --- te GEMM: A' = (x_row(n*12+t) - sgn*xa_n/12)/6, B = Wvt ---
#pragma unroll
  for (int kc = 0; kc < 2; ++kc) {
    const int k0 = kc * 32 + quad * 8;
    short8 af[2];
#pragma unroll
    for (int mi = 0; mi < 2; ++mi) {
      const int nr = m0 + wave * 32 + mi * 16 + lc;
      short8 a = {};
      if (nr < 325) {
        const float* xp = x + ((size_t)b * 3900 + (size_t)nr * 12 + t) * 64 + k0;
        const float* xap = ws + OFF_XA + ((size_t)b * 325 + nr) * 64 + k0;
        float xv[8], av[8];
        *(float4*)xv = *(const float4*)xp;
        *(float4*)(xv + 4) = *(const float4*)(xp + 4);
        *(float4*)av = *(const float4*)xap;
        *(float4*)(av + 4) = *(const float4*)(xap + 4);
#pragma unroll
        for (int u = 0; u < 8; ++u)
          a[u] = (short)f2bf((xv[u] - sgn12 * av[u]) * (1.f / 6.f));
      }
      af[mi] = a;
    }
#pragma unroll
    for (int ni = 0; ni < 4; ++ni) {
      const short8 bf_ = *(const short8*)&WVTBu[(size_t)(ni * 16 + lc) * 64 + k0];
#pragma unroll
      for (int mi = 0; mi < 2; ++mi)
        acc[mi][ni] = __builtin_amdgcn_mfma_f32_16x16x32_bf16(
            af[mi], bf_, acc[mi][ni], 0, 0, 0);
    }
  }

#pragma unroll
  for (int ni = 0; ni < 4; ++ni) {
    const int d = ni * 16 + lc;
    const float bias = bmlp[d];
#pragma unroll
    for (int mi = 0; mi < 2; ++mi) {
#pragma unroll
      for (int reg = 0; reg < 4; ++reg) {
        const int n = m0 + wave * 32 + mi * 16 + quad * 4 + reg;
        if (n >= 325) continue;
        out[((size_t)bt * 325 + n) * 64 + d] = acc[mi][ni][reg] + bias;
      }
    }
  }
}

extern "C" void kernel_launch(void* const* d_in, const int* in_sizes, int n_in,
                              void* d_out, int out_size, void* d_ws, size_t ws_size,
                              hipStream_t stream) {
  const float* x = (const float*)d_in[0];
  const float* adj = (const float*)d_in[1];
  const float* Wq_g = (const float*)d_in[2];
  const float* Wk_g = (const float*)d_in[3];
  const float* Wv_g = (const float*)d_in[4];
  // d_in[5], d_in[6] (Wq_t, Wk_t), d_in[12] (weights_Q_t), d_in[14] (t_modes):
  // dead code — temporal softmax axis == mean axis => out = vf/6.
  const float* Wv_t = (const float*)d_in[7];
  const float* Wfc1 = (const float*)d_in[8];
  const float* Wmlp = (const float*)d_in[9];
  const float* bmlp = (const float*)d_in[10];
  const float* wQ = (const float*)d_in[11];
  const int* sp_modes = (const int*)d_in[13];
  float* ws = (float*)d_ws;
  float* out = (float*)d_out;

  (void)in_sizes; (void)n_in; (void)out_size; (void)ws_size;

  hipMemsetAsync(ws + OFF_NORM, 0, 513 * sizeof(float), stream);
  k_prep<<<22, 256, 0, stream>>>(Wmlp, Wfc1, wQ, Wq_g, Wk_g, Wv_g, sp_modes, ws);
  k_mega<<<3406, 256, 0, stream>>>(x, adj, Wq_g, Wk_g, Wv_t, ws);
  k_final2<<<1152, 256, 0, stream>>>(x, bmlp, ws, out);
}

// Round 9
// 281.082 us; speedup vs baseline: 1.0700x; 1.0700x over previous
//
#include <hip/hip_runtime.h>

// Problem: B=32,T=12,N=325,D=64,H=4,HD=16,M_SP=32,M_T=6, SCALE=0.25
// Inputs fp32 (+ int32 mode lists); output fp32.
//
// Key identities used:
//  * temporal branch: softmax axis == mean axis  =>  out = vf/6. Whole branch is
//    v=x@Wv_t^T (fake (n',t') reshape r = n'*12+t'), drop Nyquist of 12-pt rfft, /6.
//    te = (vt - sgn*alt/12)/6 = ((x_s - sgn*xa_n/12)/6) @ Wvt^T  (linearity);
//    xa[b,n'] = sum_s (-1)^s x[b, n'*12+s]. VT (32MB) never materialized.
//  * rfft over n commutes with channel linear => one DFT of x, then 64x64 matmuls.
//  * GCN: Wc = W_mlp @ W_fc1 folded; out = A_rownorm @ (x @ Wc^T) + b.
//
// R16 (this round): kill the norm stage WITHOUT cross-block sync (R15's spin
// poll saturated the coherence point: mega 56->148us; reverted).
//  - Norm MFMAs fused into mega's linear2 blocks (reuse the staged XA fragments;
//    +32 MFMA/block; bucketed atomics hide behind the XCT store drain — R8/R14).
//  - Spatial's phase C (the only norm consumer) moved into k_final3: spatial
//    ends after phase B writing raw absq/absk/vfre/vfim (12.6MB, old-VT region);
//    each final3 block redoes phase C in LDS (3x redundant per bt, ~3us) —
//    mega completes first, so norms are plain loads. OFT never hits global.
//  - prep: 23 tiny blocks (tables + bucket zeroing). No memset. 3 stages total.

typedef unsigned short u16;
typedef short short8 __attribute__((ext_vector_type(8)));
typedef float floatx4 __attribute__((ext_vector_type(4)));

__device__ __forceinline__ u16 f2bf(float f) {
  union { float fp; unsigned int u; } v; v.fp = f;
  unsigned int x = v.u;
  x += 0x7FFF + ((x >> 16) & 1);   // RNE
  return (u16)(x >> 16);
}

// ---- workspace layout (float offsets; u16 arrays count as size/2 floats) ----
constexpr size_t OFF_NORM = 4096;       // 16 buckets x 32 floats (128B stride)
constexpr size_t OFF_WQA  = 8208;       // 15872   |weights_Q|
constexpr size_t OFF_ANB  = 24080;      // u16[325*352]   row-norm adj, bf16, col-pad 352
constexpr size_t OFF_TB   = 81280;      // u16[64*352]    DFT matrix bf16, rows interleaved re/im
constexpr size_t OFF_T2   = 102080;     // u16[325*64]    irfft: [n][2j]=wc_j cos, [n][2j+1]=-wc_j sin
constexpr size_t OFF_XCT  = 898912;     // u16[384*64*352] xc transposed [bt][d][n], n-pad 352
// tables + spatial intermediates live in the freed VT region:
constexpr size_t OFF_WBB  = 5224288;    // u16[192*64]  [Wc|Wq|Wk] bf16
constexpr size_t OFF_WSPB = 5230432;    // u16[192*64]  [Wq|Wk|Wv] bf16 (spatial B)
constexpr size_t OFF_WVTB = 5236576;    // u16[64*64]   Wvt bf16 (final3 te GEMM)
constexpr size_t OFF_SQQ  = 5240000;    // f32[384*2048]  sqrt(|qf|^2) per bt
constexpr size_t OFF_SQK  = 6026432;    // f32[384*2048]  sqrt(|kf|^2)
constexpr size_t OFF_VFR  = 6812864;    // f32[384*2048]  vf real
constexpr size_t OFF_VFI  = 7599296;    // f32[384*2048]  vf imag
constexpr size_t OFF_XA   = 13211488;   // f32[32*325*64]  alternating x sums

// ===========  K1 (23 blocks): tables + bucket zeroing  ===========
__global__ __launch_bounds__(256) void k_prep(const float* __restrict__ Wmlp,
                                              const float* __restrict__ Wfc1,
                                              const float* __restrict__ wQ,
                                              const float* __restrict__ Wq,
                                              const float* __restrict__ Wk,
                                              const float* __restrict__ Wv,
                                              const int* __restrict__ sp_modes,
                                              float* __restrict__ ws) {
  const int tid = threadIdx.x;
  const int blk = blockIdx.x;
  u16* WBBu = (u16*)(ws + OFF_WBB);
  if (blk == 0) {
    for (int i = tid; i < 512; i += 256) ws[OFF_NORM + i] = 0.f;
    // Wc = Wmlp @ Wfc1, straight to bf16 rows 0..63 of WBB
    for (int o = tid; o < 4096; o += 256) {
      int g = o >> 6, dd = o & 63;
      float s = 0.f;
      for (int e = 0; e < 64; ++e)
        s = fmaf(Wmlp[g * 64 + e], Wfc1[e * 64 + dd], s);
      WBBu[o] = f2bf(s);
    }
  } else if (blk < 9) {
    for (int i = (blk - 1) * 256 + tid; i < 15872; i += 2048)
      ws[OFF_WQA + i] = fabsf(wQ[i]);
  } else if (blk < 21) {
    const int j = blk - 9;
    // 12 blocks, each handles modes j, j+12, j+24
    u16* T2B = (u16*)(ws + OFF_T2);
    u16* TB = (u16*)(ws + OFF_TB);
    for (int jj = j; jj < 32; jj += 12) {
      const int f = sp_modes[jj];
      const float wgt = (f == 0) ? 1.f : 2.f;
      const int row_re = 8 * (jj >> 2) + (jj & 3);
      const int row_im = row_re + 4;
      for (int n = tid; n < 352; n += 256) {
        float c = 0.f, s = 0.f;
        if (n < 325) {
          int mm = (f * n) % 325;               // exact range reduction
          float th = 6.283185307179586f * (float)mm * (1.f / 325.f);
          c = cosf(th);
          s = sinf(th);
        }
        TB[(size_t)row_re * 352 + n] = f2bf(c);
        TB[(size_t)row_im * 352 + n] = f2bf(-s);
        if (n < 325) {
          T2B[(size_t)n * 64 + 2 * jj] = f2bf(wgt * (1.f / 325.f) * c);
          T2B[(size_t)n * 64 + 2 * jj + 1] = f2bf(-wgt * (1.f / 325.f) * s);
        }
      }
    }
  } else if (blk == 21) {
    u16* WSPBu = (u16*)(ws + OFF_WSPB);
    for (int i = tid; i < 12288; i += 256) {
      const int r = i >> 6, e = i & 63;
      const float* src = (r < 64) ? Wq : (r < 128) ? Wk : Wv;
      WSPBu[i] = f2bf(src[(size_t)(r & 63) * 64 + e]);
    }
  } else {  // blk == 22: WBB rows 64..191 = Wq | Wk (norm MFMA B-operand)
    for (int i = tid; i < 8192; i += 256) {
      const int r = i >> 6, e = i & 63;
      const float* src = (r < 64) ? Wq : Wk;
      WBBu[4096 + i] = f2bf(src[(size_t)(r & 63) * 64 + e]);
    }
  }
}

// ===========  K2: MEGA — spatialAB|linear2+norm|xa|ANB|pads|WVTB  ===========
__global__ __launch_bounds__(256) void k_mega(const float* __restrict__ x,
                                              const float* __restrict__ adj,
                                              const float* __restrict__ Wvt,
                                              float* __restrict__ ws) {
  __shared__ __align__(16) float smem[11520];   // 46,080 B (spatial XB)
  const int tid = threadIdx.x;
  const int blk = blockIdx.x;
  const int lane = tid & 63, wv = tid >> 6;
  const int lc = lane & 15, quad = lane >> 4;

  if (blk < 384) {
    // ================= spatial phases A+B per bt =================
    const int bt = blk;
    u16* XBu = (u16*)smem;                       // [64 e][360 n]

    const u16* TB = (const u16*)(ws + OFF_TB);
    const u16* WSPBu = (const u16*)(ws + OFF_WSPB);
    const float* xb = x + (size_t)bt * 20800;
    const int br = tid & 31, be0 = (tid >> 5) * 8;

    // ---- stage whole x-tile -> XB (bf16, [e][n]) ----
    {
      float va[4][8];
#pragma unroll
      for (int g = 0; g < 3; ++g) {
        const int nkc = (g < 2) ? 4 : 3;
#pragma unroll
        for (int u = 0; u < 4; ++u) {
          if (u >= nkc) break;
          const int k0 = (g * 4 + u) * 32;
          if (k0 + br < 325) {
            const float* src = xb + (size_t)(k0 + br) * 64 + be0;
            *(float4*)&va[u][0] = *(const float4*)src;
            *(float4*)&va[u][4] = *(const float4*)(src + 4);
          } else {
#pragma unroll
            for (int w = 0; w < 8; ++w) va[u][w] = 0.f;
          }
        }
#pragma unroll
        for (int u = 0; u < 4; ++u) {
          if (u >= nkc) break;
          const int k0 = (g * 4 + u) * 32;
#pragma unroll
          for (int w = 0; w < 8; ++w)
            XBu[(be0 + w) * 360 + k0 + br] = f2bf(va[u][w]);
        }
      }
    }
    __syncthreads();

    // ---- Phase A: DFT GEMM, barrier-free ----
    floatx4 accA[4] = {};
#pragma unroll
    for (int kc = 0; kc < 11; ++kc) {
      const short8 af = *(const short8*)&TB[(size_t)(16 * wv + lc) * 352 + kc * 32 + quad * 8];
#pragma unroll
      for (int t = 0; t < 4; ++t) {
        const short8 bf_ = *(const short8*)&XBu[(t * 16 + lc) * 360 + kc * 32 + quad * 8];
        accA[t] = __builtin_amdgcn_mfma_f32_16x16x32_bf16(af, bf_, accA[t], 0, 0, 0);
      }
    }
    __syncthreads();   // all XB reads done; first 10,240B reused as xfl2

    u16* xfl2 = XBu;
#pragma unroll
    for (int t = 0; t < 4; ++t)
#pragma unroll
      for (int r = 0; r < 4; ++r)
        xfl2[(t >> 1) * 2560 + (16 * wv + quad * 4 + r) * 40 + (t & 1) * 16 + lc] =
            f2bf(accA[t][r]);
    __syncthreads();

    // ---- Phase B: projection GEMM ----
    floatx4 acc2[12] = {};
#pragma unroll
    for (int kc2 = 0; kc2 < 2; ++kc2) {
      const short8 af2 = *(const short8*)&xfl2[kc2 * 2560 + (16 * wv + lc) * 40 + quad * 8];
#pragma unroll
      for (int t = 0; t < 12; ++t) {
        const short8 bf2 = *(const short8*)&WSPBu[(t * 16 + lc) * 64 + kc2 * 32 + quad * 8];
        acc2[t] = __builtin_amdgcn_mfma_f32_16x16x32_bf16(af2, bf2, acc2[t], 0, 0, 0);
      }
    }

    // ---- write raw intermediates for final3's phase C ----
    float* g_sqq = ws + OFF_SQQ + (size_t)bt * 2048;
    float* g_sqk = ws + OFF_SQK + (size_t)bt * 2048;
    float* g_vfr = ws + OFF_VFR + (size_t)bt * 2048;
    float* g_vfi = ws + OFF_VFI + (size_t)bt * 2048;
    {
      const int fb = 8 * wv + ((quad >= 2) ? 4 : 0);
      const int isim = quad & 1;
#pragma unroll
      for (int t = 0; t < 12; ++t) {
        const int mat = t >> 2;
        const int d = (t & 3) * 16 + lc;
#pragma unroll
        for (int r = 0; r < 4; ++r) {
          const float v = acc2[t][r];
          if (mat == 2) {
            if (isim) g_vfi[(fb + r) * 64 + d] = v;
            else g_vfr[(fb + r) * 64 + d] = v;
          } else {
            const float s2 = v * v + __shfl_xor(v * v, 16);
            if (!isim) {
              if (mat == 0) g_sqq[(fb + r) * 64 + d] = sqrtf(s2);
              else g_sqk[(fb + r) * 64 + d] = sqrtf(s2);
            }
          }
        }
      }
    }
  } else if (blk < 1359) {
    // ================= linear2 + fused norm: xc -> XCT, ||q||^2/||k||^2 =================
    const int blk2 = blk - 384;
    u16* XAu = (u16*)smem;                 // [128][72] u16 = 18,432B; reused as xcT
    float* red = smem + 4608;              // 16 floats, past XAu
    const size_t base = (size_t)blk2 * 128;
    const u16* WBBu = (const u16*)(ws + OFF_WBB);

    for (int i = tid; i < 2048; i += 256) {
      const int row = i >> 4, e0 = (i & 15) * 4;
      const float4 v = *(const float4*)(x + (base + row) * 64 + e0);
      u16* dst = &XAu[row * 72 + e0];
      dst[0] = f2bf(v.x); dst[1] = f2bf(v.y); dst[2] = f2bf(v.z); dst[3] = f2bf(v.w);
    }
    __syncthreads();

    short8 afc[2][2];
#pragma unroll
    for (int kc = 0; kc < 2; ++kc)
#pragma unroll
      for (int mi = 0; mi < 2; ++mi)
        afc[mi][kc] = *(const short8*)&XAu[(32 * wv + 16 * mi + lc) * 72 + kc * 32 + quad * 8];

    floatx4 acc[2][4] = {};
#pragma unroll
    for (int kc = 0; kc < 2; ++kc)
#pragma unroll
      for (int ni = 0; ni < 4; ++ni) {
        const short8 bf_ = *(const short8*)&WBBu[(ni * 16 + lc) * 64 + kc * 32 + quad * 8];
#pragma unroll
        for (int mi = 0; mi < 2; ++mi)
          acc[mi][ni] = __builtin_amdgcn_mfma_f32_16x16x32_bf16(afc[mi][kc], bf_, acc[mi][ni], 0, 0, 0);
      }

    // fused norm: reuse afc against Wq (WBB rows 64..127) / Wk (128..191)
    float sq = 0.f, sk = 0.f;
#pragma unroll
    for (int ni = 0; ni < 8; ++ni) {
      floatx4 a0 = {}, a1 = {};
#pragma unroll
      for (int kc = 0; kc < 2; ++kc) {
        const short8 bf_ = *(const short8*)&WBBu[
            (size_t)(64 + (ni >> 2) * 64 + (ni & 3) * 16 + lc) * 64 + kc * 32 + quad * 8];
        a0 = __builtin_amdgcn_mfma_f32_16x16x32_bf16(afc[0][kc], bf_, a0, 0, 0, 0);
        a1 = __builtin_amdgcn_mfma_f32_16x16x32_bf16(afc[1][kc], bf_, a1, 0, 0, 0);
      }
      float s = 0.f;
#pragma unroll
      for (int reg = 0; reg < 4; ++reg)
        s = fmaf(a0[reg], a0[reg], fmaf(a1[reg], a1[reg], s));
      if (ni < 4) sq += s; else sk += s;
    }
    for (int off = 32; off > 0; off >>= 1) {
      sq += __shfl_down(sq, off);
      sk += __shfl_down(sk, off);
    }
    if (lane == 0) { red[wv] = sq; red[8 + wv] = sk; }
    __syncthreads();   // also: all afc reads of XAu complete

    u16* xcT = XAu;    // [64 d][132]
#pragma unroll
    for (int ni = 0; ni < 4; ++ni)
#pragma unroll
      for (int mi = 0; mi < 2; ++mi)
#pragma unroll
        for (int reg = 0; reg < 4; ++reg)
          xcT[(ni * 16 + lc) * 132 + 32 * wv + 16 * mi + quad * 4 + reg] =
              f2bf(acc[mi][ni][reg]);
    __syncthreads();
    u16* XCT = (u16*)(ws + OFF_XCT);
    for (int i = tid; i < 8192; i += 256) {
      const int d = i >> 7, r = i & 127;
      const unsigned int row = (unsigned int)(base + r);
      const unsigned int bt = row / 325u;
      const unsigned int n = row - bt * 325u;
      XCT[(size_t)bt * 22528 + (size_t)d * 352 + n] = xcT[d * 132 + r];
    }
    if (tid == 0)
      atomicAdd(&ws[OFF_NORM + 32 * (size_t)(blk2 & 15) + 0],
                red[0] + red[1] + red[2] + red[3]);
    if (tid == 1)
      atomicAdd(&ws[OFF_NORM + 32 * (size_t)(blk2 & 15) + 1],
                red[8] + red[9] + red[10] + red[11]);
  } else if (blk < 2009) {
    // ================= xa: alternating sums of x =================
    const int idx = (blk - 1359) * 256 + tid;
    if (idx >= 32 * 325 * 16) return;
    const int dq = idx & 15;            // float4 slot
    const int n = (idx >> 4) % 325;
    const int b = idx / (16 * 325);
    const float* xp = x + ((size_t)b * 3900 + (size_t)n * 12) * 64 + dq * 4;
    float4 s = make_float4(0.f, 0.f, 0.f, 0.f);
    float sign = 1.f;
    for (int k = 0; k < 12; ++k) {
      const float4 v = *(const float4*)(xp + (size_t)k * 64);
      s.x += sign * v.x; s.y += sign * v.y; s.z += sign * v.z; s.w += sign * v.w;
      sign = -sign;
    }
    *(float4*)(ws + OFF_XA + ((size_t)b * 325 + n) * 64 + dq * 4) = s;
  } else if (blk < 2334) {
    // ================= ANB: adj row-normalize -> bf16 (final3-only) =================
    const int n = blk - 2009;           // < 325
    float* red = smem;
    float p = 0.f;
    for (int k = tid; k < 325; k += 256) p += adj[n * 325 + k];
    red[tid] = p;
    __syncthreads();
    for (int s2 = 128; s2 > 0; s2 >>= 1) {
      if (tid < s2) red[tid] += red[tid + s2];
      __syncthreads();
    }
    const float inv = 1.f / red[0];
    u16* ANB = (u16*)(ws + OFF_ANB);
    for (int k = tid; k < 352; k += 256)
      ANB[(size_t)n * 352 + k] = (k < 325) ? f2bf(adj[n * 325 + k] * inv) : (u16)0;
  } else if (blk < 2430) {
    // ================= XCT n-pad zeroing (final3-only) =================
    const int idx = (blk - 2334) * 256 + tid;   // < 24576 = 384*64
    u16* p = (u16*)(ws + OFF_XCT) + (size_t)(idx >> 6) * 22528 + (size_t)(idx & 63) * 352;
    for (int c = 325; c < 352; ++c) p[c] = 0;
  } else {
    // ================= WVTB (final3-only) =================
    u16* WVTBu = (u16*)(ws + OFF_WVTB);
    for (int i = tid; i < 4096; i += 256) WVTBu[i] = f2bf(Wvt[i]);
  }
}

// =======  K3 (R16): phase C (in-LDS softmax+OFT) + MFMA C = AN@XCT + T2@oft + TE@Wvt  =======
__global__ __launch_bounds__(256) void k_final3(const float* __restrict__ x,
                                                const float* __restrict__ bmlp,
                                                float* __restrict__ ws,
                                                float* __restrict__ out) {
  __shared__ __align__(16) float smem[8448];    // 33,792 B
  float* asq = smem;                            // [32][64]  sqrt|qf|
  float* askl = smem + 2048;                    // [32][64]  0.25*inv_nk*sqrt|kf|
  float* wbar = smem + 4096;                    // [32][64]
  unsigned int* oftu = (unsigned int*)(smem + 6144);   // [64 d][36] u32 (stride 72 u16)
  const u16* oft16 = (const u16*)oftu;

  const int tid = threadIdx.x;
  const int bt = blockIdx.x / 3, mc = blockIdx.x % 3;
  const int m0 = mc * 128;
  const int wave = tid >> 6, lane = tid & 63;
  const int quad = lane >> 4, lc = lane & 15;

  // ---- norms (mega complete; plain broadcast loads) ----
  float nq = 0.f, nk = 0.f;
#pragma unroll
  for (int k2 = 0; k2 < 16; ++k2) {
    const float2 v = *(const float2*)(ws + OFF_NORM + 32 * (size_t)k2);
    nq += v.x; nk += v.y;
  }
  const float inv_nq = rsqrtf(nq);
  const float inv_nk = rsqrtf(nk);

  // ---- phase C: load intermediates, softmax, build oft in LDS ----
  for (int i = tid; i < 2048; i += 256) {
    asq[i] = ws[OFF_SQQ + (size_t)bt * 2048 + i];
    askl[i] = 0.25f * inv_nk * ws[OFF_SQK + (size_t)bt * 2048 + i];
    wbar[i] = 0.f;
  }
  __syncthreads();
  {
    const int d = tid & 63, fb2 = tid >> 6, hd = d & 15;
    const float* wqa = ws + OFF_WQA;
    float wacc[32];
#pragma unroll
    for (int j = 0; j < 32; ++j) wacc[j] = 0.f;
    for (int r8 = 0; r8 < 8; ++r8) {
      const int m = fb2 + (r8 << 2);
      const float aq = inv_nq * asq[m * 64 + d];
      float sv[32];
      float mx = -1e30f;
#pragma unroll
      for (int j = 0; j < 32; ++j) {
        const float a = (j == 0) ? aq : wqa[(m * 31 + (j - 1)) * 16 + hd];
        const float s = askl[j * 64 + d] * a;
        sv[j] = s;
        mx = fmaxf(mx, s);
      }
      float sum = 0.f;
#pragma unroll
      for (int j = 0; j < 32; ++j) {
        const float ev = __expf(sv[j] - mx);
        sv[j] = ev;
        sum += ev;
      }
      const float sc = 0.03125f / sum;
#pragma unroll
      for (int j = 0; j < 32; ++j) wacc[j] += sv[j] * sc;
    }
#pragma unroll
    for (int j = 0; j < 32; ++j) atomicAdd(&wbar[j * 64 + d], wacc[j]);
  }
  __syncthreads();
  for (int i2 = tid; i2 < 2048; i2 += 256) {
    const int j = i2 >> 6, d = i2 & 63;
    const float w = wbar[j * 64 + d];
    const unsigned int lo = f2bf(ws[OFF_VFR + (size_t)bt * 2048 + j * 64 + d] * w);
    const unsigned int hi = f2bf(ws[OFF_VFI + (size_t)bt * 2048 + j * 64 + d] * w);
    oftu[d * 36 + j] = lo | (hi << 16);
  }
  __syncthreads();

  // ---- main GEMM ----
  const u16* ANB = (const u16*)(ws + OFF_ANB);
  const u16* T2B = (const u16*)(ws + OFF_T2);
  const u16* XCT = (const u16*)(ws + OFF_XCT) + (size_t)bt * 22528;
  const u16* WVTBu = (const u16*)(ws + OFF_WVTB);

  const int b = bt / 12, t = bt - b * 12;
  const float sgn12 = ((t & 1) ? -1.f : 1.f) * (1.f / 12.f);

  floatx4 acc[2][4] = {};

#pragma unroll
  for (int c13 = 0; c13 < 13; ++c13) {
    const bool gcn = (c13 < 11);
    const int acol = gcn ? c13 * 32 : (c13 - 11) * 32;
    short8 af[2], bf_[4];
#pragma unroll
    for (int mi = 0; mi < 2; ++mi) {
      const int gr = m0 + wave * 32 + mi * 16 + lc;
      short8 a = {};
      if (gr < 325)
        a = gcn ? *(const short8*)&ANB[(size_t)gr * 352 + acol + quad * 8]
                : *(const short8*)&T2B[(size_t)gr * 64 + acol + quad * 8];
      af[mi] = a;
    }
#pragma unroll
    for (int ni = 0; ni < 4; ++ni)
      bf_[ni] = gcn ? *(const short8*)&XCT[(size_t)(ni * 16 + lc) * 352 + acol + quad * 8]
                    : *(const short8*)&oft16[(ni * 16 + lc) * 72 + acol + quad * 8];
#pragma unroll
    for (int mi = 0; mi < 2; ++mi)
#pragma unroll
      for (int ni = 0; ni < 4; ++ni)
        acc[mi][ni] = __builtin_amdgcn_mfma_f32_16x16x32_bf16(
            af[mi], bf_[ni], acc[mi][ni], 0, 0, 0);
  }

  // --- te GEMM: A' = (x_row(n*12+t) - sgn*xa_n/12)/6, B = Wvt ---
#pragma unroll
  for (int kc = 0; kc < 2; ++kc) {
    const int k0 = kc * 32 + quad * 8;
    short8 af[2];
#pragma unroll
    for (int mi = 0; mi < 2; ++mi) {
      const int nr = m0 + wave * 32 + mi * 16 + lc;
      short8 a = {};
      if (nr < 325) {
        const float* xp = x + ((size_t)b * 3900 + (size_t)nr * 12 + t) * 64 + k0;
        const float* xap = ws + OFF_XA + ((size_t)b * 325 + nr) * 64 + k0;
        float xv[8], av[8];
        *(float4*)xv = *(const float4*)xp;
        *(float4*)(xv + 4) = *(const float4*)(xp + 4);
        *(float4*)av = *(const float4*)xap;
        *(float4*)(av + 4) = *(const float4*)(xap + 4);
#pragma unroll
        for (int u = 0; u < 8; ++u)
          a[u] = (short)f2bf((xv[u] - sgn12 * av[u]) * (1.f / 6.f));
      }
      af[mi] = a;
    }
#pragma unroll
    for (int ni = 0; ni < 4; ++ni) {
      const short8 bf_ = *(const short8*)&WVTBu[(size_t)(ni * 16 + lc) * 64 + k0];
#pragma unroll
      for (int mi = 0; mi < 2; ++mi)
        acc[mi][ni] = __builtin_amdgcn_mfma_f32_16x16x32_bf16(
            af[mi], bf_, acc[mi][ni], 0, 0, 0);
    }
  }

#pragma unroll
  for (int ni = 0; ni < 4; ++ni) {
    const int d = ni * 16 + lc;
    const float bias = bmlp[d];
#pragma unroll
    for (int mi = 0; mi < 2; ++mi) {
#pragma unroll
      for (int reg = 0; reg < 4; ++reg) {
        const int n = m0 + wave * 32 + mi * 16 + quad * 4 + reg;
        if (n >= 325) continue;
        out[((size_t)bt * 325 + n) * 64 + d] = acc[mi][ni][reg] + bias;
      }
    }
  }
}

extern "C" void kernel_launch(void* const* d_in, const int* in_sizes, int n_in,
                              void* d_out, int out_size, void* d_ws, size_t ws_size,
                              hipStream_t stream) {
  const float* x = (const float*)d_in[0];
  const float* adj = (const float*)d_in[1];
  const float* Wq_g = (const float*)d_in[2];
  const float* Wk_g = (const float*)d_in[3];
  const float* Wv_g = (const float*)d_in[4];
  // d_in[5], d_in[6] (Wq_t, Wk_t), d_in[12] (weights_Q_t), d_in[14] (t_modes):
  // dead code — temporal softmax axis == mean axis => out = vf/6.
  const float* Wv_t = (const float*)d_in[7];
  const float* Wfc1 = (const float*)d_in[8];
  const float* Wmlp = (const float*)d_in[9];
  const float* bmlp = (const float*)d_in[10];
  const float* wQ = (const float*)d_in[11];
  const int* sp_modes = (const int*)d_in[13];
  float* ws = (float*)d_ws;
  float* out = (float*)d_out;

  (void)in_sizes; (void)n_in; (void)out_size; (void)ws_size;

  k_prep<<<23, 256, 0, stream>>>(Wmlp, Wfc1, wQ, Wq_g, Wk_g, Wv_g, sp_modes, ws);
  k_mega<<<2431, 256, 0, stream>>>(x, adj, Wv_t, ws);
  k_final3<<<1152, 256, 0, stream>>>(x, bmlp, ws, out);
}

// Round 10
// 226.663 us; speedup vs baseline: 1.3270x; 1.2401x over previous
//
#include <hip/hip_runtime.h>

// Problem: B=32,T=12,N=325,D=64,H=4,HD=16,M_SP=32,M_T=6, SCALE=0.25
// Inputs fp32 (+ int32 mode lists); output fp32.
//
// Key identities used:
//  * temporal branch: softmax axis == mean axis  =>  out = vf/6. Whole branch is
//    v=x@Wv_t^T (fake (n',t') reshape r = n'*12+t'), drop Nyquist of 12-pt rfft, /6.
//    te = (vt - sgn*alt/12)/6 = ((x_s - sgn*xa_n/12)/6) @ Wvt^T  (linearity);
//    xa[b,n'] = sum_s (-1)^s x[b, n'*12+s]. VT (32MB) never materialized.
//  * rfft over n commutes with channel linear => one DFT of x, then 64x64 matmuls.
//  * GCN: Wc = W_mlp @ W_fc1 folded; out = A_rownorm @ (x @ Wc^T) + b.
//
// R17 (this round): REVERT to R14 base (best measured, 235us; R15 spin and R16
// consumer-move both regressed) + two safe independent wins:
//  1. k_prep0 (2 blocks, replaces memset launch): zero norm buckets + convert
//     Wq|Wk to bf16 fragment table WQKB. prep's 975 norm blocks were spending
//     128 f2bf/thread re-converting weights per block; now they load short8
//     fragments directly -> memory-bound.
//  2. final2 XCD swizzle: wg=(bid&7)*144+(bid>>3) (bijective, 1152=8x144) so
//     the 3 mc-blocks sharing one bt's 22.5KB XCT panel land on the SAME XCD
//     L2 (consecutive blockIdx round-robin across XCDs otherwise -> 3x HBM).

typedef unsigned short u16;
typedef short short8 __attribute__((ext_vector_type(8)));
typedef float floatx4 __attribute__((ext_vector_type(4)));

__device__ __forceinline__ u16 f2bf(float f) {
  union { float fp; unsigned int u; } v; v.fp = f;
  unsigned int x = v.u;
  x += 0x7FFF + ((x >> 16) & 1);   // RNE
  return (u16)(x >> 16);
}

// ---- workspace layout (float offsets; u16 arrays count as size/2 floats) ----
constexpr size_t OFF_NORM = 4096;       // 16 buckets x 32 floats (128B stride);
                                        // bucket k: [32k]=sum q^2, [32k+1]=sum k^2
constexpr size_t OFF_WQA  = 8208;       // 15872   |weights_Q|
constexpr size_t OFF_ANB  = 24080;      // u16[325*352]   row-norm adj, bf16, col-pad 352
constexpr size_t OFF_TB   = 81280;      // u16[64*352]    DFT matrix bf16, rows interleaved re/im
constexpr size_t OFF_T2   = 102080;     // u16[325*64]    irfft: [n][2j]=wc_j cos, [n][2j+1]=-wc_j sin
constexpr size_t OFF_OFT  = 112480;     // u16[384*64*64] spectrum [bt][d][2j|2j+1] (re,im)
constexpr size_t OFF_XCT  = 898912;     // u16[384*64*352] xc transposed [bt][d][n], n-pad 352
// weight tables live in the freed VT region (no aliasing with XA)
constexpr size_t OFF_WBB  = 5224288;    // u16[64*64]   Wc bf16 (mega/linear2 B)
constexpr size_t OFF_WSPB = 5226336;    // u16[192*64]  [Wq|Wk|Wv] bf16 (spatial B)
constexpr size_t OFF_WVTB = 5232480;    // u16[64*64]   Wvt bf16 (k_final2 te GEMM)
constexpr size_t OFF_WQKB = 5234528;    // u16[128*64]  [Wq|Wk] bf16 (norm MFMA B)
constexpr size_t OFF_XA   = 13211488;   // f32[32*325*64]  alternating x sums

// ===========  K0 (2 blocks): zero buckets + WQKB bf16 table  ===========
__global__ __launch_bounds__(256) void k_prep0(const float* __restrict__ Wq,
                                               const float* __restrict__ Wk,
                                               float* __restrict__ ws) {
  const int tid = threadIdx.x;
  const int blk = blockIdx.x;
  u16* WQKB = (u16*)(ws + OFF_WQKB);
  if (blk == 0) {
    for (int i = tid; i < 512; i += 256) ws[OFF_NORM + i] = 0.f;
    for (int i = tid; i < 4096; i += 256) WQKB[i] = f2bf(Wq[i]);
  } else {
    for (int i = tid; i < 4096; i += 256) WQKB[4096 + i] = f2bf(Wk[i]);
  }
}

// ===========  K1: weights bf16, |wQ|, twiddles, NORM (bucketed atomics)  ===========
__global__ __launch_bounds__(256) void k_prep(const float* __restrict__ x,
                                              const float* __restrict__ Wmlp,
                                              const float* __restrict__ Wfc1,
                                              const float* __restrict__ wQ,
                                              const float* __restrict__ Wq,
                                              const float* __restrict__ Wk,
                                              const float* __restrict__ Wv,
                                              const int* __restrict__ sp_modes,
                                              float* __restrict__ ws) {
  __shared__ float red[256];
  __shared__ __align__(16) u16 XA[128 * 72];   // norm blocks only
  const int tid = threadIdx.x;
  const int blk = blockIdx.x;
  u16* WBBu = (u16*)(ws + OFF_WBB);
  if (blk >= 22) {
    // ---- norm blocks: partial ||q||^2, ||k||^2 over 128 rows of x -> bucketed atomics ----
    const int blk2 = blk - 22;               // < 975
    const int wv = tid >> 6, lane = tid & 63, lc = lane & 15, quad = lane >> 4;
    const size_t base = (size_t)blk2 * 128;
    const u16* WQKB = (const u16*)(ws + OFF_WQKB);
    for (int i = tid; i < 2048; i += 256) {
      const int row = i >> 4, e0 = (i & 15) * 4;
      const float4 v = *(const float4*)(x + (base + row) * 64 + e0);
      u16* dst = &XA[row * 72 + e0];
      dst[0] = f2bf(v.x); dst[1] = f2bf(v.y); dst[2] = f2bf(v.z); dst[3] = f2bf(v.w);
    }
    __syncthreads();
    floatx4 acc[2][8] = {};
#pragma unroll
    for (int kc = 0; kc < 2; ++kc) {
      short8 af[2];
#pragma unroll
      for (int mi = 0; mi < 2; ++mi)
        af[mi] = *(const short8*)&XA[(32 * wv + 16 * mi + lc) * 72 + kc * 32 + quad * 8];
#pragma unroll
      for (int ni = 0; ni < 8; ++ni) {
        const short8 bf_ = *(const short8*)&WQKB[
            (size_t)(((ni >> 2) << 6) + (ni & 3) * 16 + lc) * 64 + kc * 32 + quad * 8];
#pragma unroll
        for (int mi = 0; mi < 2; ++mi)
          acc[mi][ni] = __builtin_amdgcn_mfma_f32_16x16x32_bf16(af[mi], bf_, acc[mi][ni], 0, 0, 0);
      }
    }
    float sq = 0.f, sk = 0.f;
#pragma unroll
    for (int mi = 0; mi < 2; ++mi)
#pragma unroll
      for (int reg = 0; reg < 4; ++reg) {
#pragma unroll
        for (int ni = 0; ni < 4; ++ni) {
          const float v = acc[mi][ni][reg];
          sq = fmaf(v, v, sq);
        }
#pragma unroll
        for (int ni = 4; ni < 8; ++ni) {
          const float v = acc[mi][ni][reg];
          sk = fmaf(v, v, sk);
        }
      }
    for (int off = 32; off > 0; off >>= 1) {
      sq += __shfl_down(sq, off);
      sk += __shfl_down(sk, off);
    }
    if (lane == 0) { red[wv] = sq; red[8 + wv] = sk; }
    __syncthreads();
    if (tid == 0) {
      const size_t bucket = OFF_NORM + 32 * (size_t)(blk2 & 15);
      atomicAdd(&ws[bucket + 0], red[0] + red[1] + red[2] + red[3]);
      atomicAdd(&ws[bucket + 1], red[8] + red[9] + red[10] + red[11]);
    }
    return;
  }
  if (blk == 0) {
    // Wc = Wmlp @ Wfc1, straight to bf16
    for (int o = tid; o < 4096; o += 256) {
      int g = o >> 6, dd = o & 63;
      float s = 0.f;
      for (int e = 0; e < 64; ++e)
        s = fmaf(Wmlp[g * 64 + e], Wfc1[e * 64 + dd], s);
      WBBu[o] = f2bf(s);
    }
  } else if (blk < 9) {
    for (int i = (blk - 1) * 256 + tid; i < 15872; i += 2048)
      ws[OFF_WQA + i] = fabsf(wQ[i]);
  } else if (blk < 21) {
    const int j = blk - 9;
    // 12 blocks, each handles modes j, j+12, j+24
    u16* T2B = (u16*)(ws + OFF_T2);
    u16* TB = (u16*)(ws + OFF_TB);
    for (int jj = j; jj < 32; jj += 12) {
      const int f = sp_modes[jj];
      const float wgt = (f == 0) ? 1.f : 2.f;
      const int row_re = 8 * (jj >> 2) + (jj & 3);
      const int row_im = row_re + 4;
      for (int n = tid; n < 352; n += 256) {
        float c = 0.f, s = 0.f;
        if (n < 325) {
          int mm = (f * n) % 325;               // exact range reduction
          float th = 6.283185307179586f * (float)mm * (1.f / 325.f);
          c = cosf(th);
          s = sinf(th);
        }
        TB[(size_t)row_re * 352 + n] = f2bf(c);
        TB[(size_t)row_im * 352 + n] = f2bf(-s);
        if (n < 325) {
          T2B[(size_t)n * 64 + 2 * jj] = f2bf(wgt * (1.f / 325.f) * c);
          T2B[(size_t)n * 64 + 2 * jj + 1] = f2bf(-wgt * (1.f / 325.f) * s);
        }
      }
    }
  } else {  // blk == 21
    u16* WSPBu = (u16*)(ws + OFF_WSPB);
    for (int i = tid; i < 12288; i += 256) {
      const int r = i >> 6, e = i & 63;
      const float* src = (r < 64) ? Wq : (r < 128) ? Wk : Wv;
      WSPBu[i] = f2bf(src[(size_t)(r & 63) * 64 + e]);
    }
  }
}

// ===========  K2: MEGA — spatial|linear2|xa|ANB|pads|WVTB  ===========
__global__ __launch_bounds__(256) void k_mega(const float* __restrict__ x,
                                              const float* __restrict__ adj,
                                              const float* __restrict__ Wvt,
                                              float* __restrict__ ws) {
  __shared__ __align__(16) float smem[12800];   // 51,200 B (spatial worst case)
  const int tid = threadIdx.x;
  const int blk = blockIdx.x;
  const int lane = tid & 63, wv = tid >> 6;
  const int lc = lane & 15, quad = lane >> 4;

  if (blk < 384) {
    // ================= spatial branch per bt =================
    const int bt = blk;
    u16* XBu = (u16*)smem;                       // [64 e][360 n]
    // norm scalars: sum the 16 buckets (broadcast reads, prep complete)
    float g_nq = 0.f, g_nk = 0.f;
#pragma unroll
    for (int k2 = 0; k2 < 16; ++k2) {
      const float2 v = *(const float2*)(ws + OFF_NORM + 32 * (size_t)k2);
      g_nq += v.x; g_nk += v.y;
    }

    const u16* TB = (const u16*)(ws + OFF_TB);
    const u16* WSPBu = (const u16*)(ws + OFF_WSPB);
    const float* xb = x + (size_t)bt * 20800;
    const int br = tid & 31, be0 = (tid >> 5) * 8;

    // ---- stage whole x-tile -> XB (bf16, [e][n]) ----
    {
      float va[4][8];
#pragma unroll
      for (int g = 0; g < 3; ++g) {
        const int nkc = (g < 2) ? 4 : 3;
#pragma unroll
        for (int u = 0; u < 4; ++u) {
          if (u >= nkc) break;
          const int k0 = (g * 4 + u) * 32;
          if (k0 + br < 325) {
            const float* src = xb + (size_t)(k0 + br) * 64 + be0;
            *(float4*)&va[u][0] = *(const float4*)src;
            *(float4*)&va[u][4] = *(const float4*)(src + 4);
          } else {
#pragma unroll
            for (int w = 0; w < 8; ++w) va[u][w] = 0.f;
          }
        }
#pragma unroll
        for (int u = 0; u < 4; ++u) {
          if (u >= nkc) break;
          const int k0 = (g * 4 + u) * 32;
#pragma unroll
          for (int w = 0; w < 8; ++w)
            XBu[(be0 + w) * 360 + k0 + br] = f2bf(va[u][w]);
        }
      }
    }
    __syncthreads();

    // ---- Phase A: DFT GEMM, barrier-free ----
    floatx4 accA[4] = {};
#pragma unroll
    for (int kc = 0; kc < 11; ++kc) {
      const short8 af = *(const short8*)&TB[(size_t)(16 * wv + lc) * 352 + kc * 32 + quad * 8];
#pragma unroll
      for (int t = 0; t < 4; ++t) {
        const short8 bf_ = *(const short8*)&XBu[(t * 16 + lc) * 360 + kc * 32 + quad * 8];
        accA[t] = __builtin_amdgcn_mfma_f32_16x16x32_bf16(af, bf_, accA[t], 0, 0, 0);
      }
    }
    __syncthreads();   // all XB reads done; first 10,240B reused as xfl2

    u16* xfl2 = XBu;
#pragma unroll
    for (int t = 0; t < 4; ++t)
#pragma unroll
      for (int r = 0; r < 4; ++r)
        xfl2[(t >> 1) * 2560 + (16 * wv + quad * 4 + r) * 40 + (t & 1) * 16 + lc] =
            f2bf(accA[t][r]);
    __syncthreads();

    // ---- Phase B: projection GEMM ----
    floatx4 acc2[12] = {};
#pragma unroll
    for (int kc2 = 0; kc2 < 2; ++kc2) {
      const short8 af2 = *(const short8*)&xfl2[kc2 * 2560 + (16 * wv + lc) * 40 + quad * 8];
#pragma unroll
      for (int t = 0; t < 12; ++t) {
        const short8 bf2 = *(const short8*)&WSPBu[(t * 16 + lc) * 64 + kc2 * 32 + quad * 8];
        acc2[t] = __builtin_amdgcn_mfma_f32_16x16x32_bf16(af2, bf2, acc2[t], 0, 0, 0);
      }
    }
    __syncthreads();

    // ---- Phase C ----
    float* sq_q = smem + 2560;      // [32][64]
    float* sq_k = smem + 4608;      // [32][64] -> absk*SCALE/||k||
    float* vfre = smem + 6656;
    float* vfim = smem + 8704;
    float* wbar = smem + 10752;
    for (int i = tid; i < 2048; i += 256) wbar[i] = 0.f;
    {
      const int fb = 8 * wv + ((quad >= 2) ? 4 : 0);
      const int isim = quad & 1;
#pragma unroll
      for (int t = 0; t < 12; ++t) {
        const int mat = t >> 2;
        const int d = (t & 3) * 16 + lc;
#pragma unroll
        for (int r = 0; r < 4; ++r) {
          const float v = acc2[t][r];
          if (mat == 2) {
            if (isim) vfim[(fb + r) * 64 + d] = v;
            else vfre[(fb + r) * 64 + d] = v;
          } else {
            const float s2 = v * v + __shfl_xor(v * v, 16);
            if (!isim) {
              if (mat == 0) sq_q[(fb + r) * 64 + d] = s2;
              else sq_k[(fb + r) * 64 + d] = s2;
            }
          }
        }
      }
    }
    __syncthreads();
    const float inv_nq = rsqrtf(g_nq);
    const float inv_nk = rsqrtf(g_nk);
    for (int i = tid; i < 2048; i += 256)
      sq_k[i] = 0.25f * inv_nk * sqrtf(sq_k[i]);
    __syncthreads();
    {
      const int d = tid & 63, fb2 = tid >> 6, hd = d & 15;
      const float* wqa = ws + OFF_WQA;
      float wacc[32];
#pragma unroll
      for (int j = 0; j < 32; ++j) wacc[j] = 0.f;
      for (int r8 = 0; r8 < 8; ++r8) {
        const int m = fb2 + (r8 << 2);
        const float aq = inv_nq * sqrtf(sq_q[m * 64 + d]);
        float sv[32];
        float mx = -1e30f;
#pragma unroll
        for (int j = 0; j < 32; ++j) {
          const float a = (j == 0) ? aq : wqa[(m * 31 + (j - 1)) * 16 + hd];
          const float s = sq_k[j * 64 + d] * a;
          sv[j] = s;
          mx = fmaxf(mx, s);
        }
        float sum = 0.f;
#pragma unroll
        for (int j = 0; j < 32; ++j) {
          const float ev = __expf(sv[j] - mx);
          sv[j] = ev;
          sum += ev;
        }
        const float sc = 0.03125f / sum;
#pragma unroll
        for (int j = 0; j < 32; ++j) wacc[j] += sv[j] * sc;
      }
#pragma unroll
      for (int j = 0; j < 32; ++j) atomicAdd(&wbar[j * 64 + d], wacc[j]);
    }
    __syncthreads();
    unsigned int* OFTu = (unsigned int*)(ws + OFF_OFT) + (size_t)bt * 2048;
    for (int i2 = tid; i2 < 2048; i2 += 256) {
      const int d = i2 >> 5, j = i2 & 31;
      const float w = wbar[j * 64 + d];
      const unsigned int lo = f2bf(vfre[j * 64 + d] * w);
      const unsigned int hi = f2bf(vfim[j * 64 + d] * w);
      OFTu[i2] = lo | (hi << 16);
    }
  } else if (blk < 1359) {
    // ================= linear2 (Wc only): xc -> XCT =================
    const int blk2 = blk - 384;
    u16* XAu = (u16*)smem;                 // [128][72] u16; reused as xcT[64][132]
    const size_t base = (size_t)blk2 * 128;
    const u16* WBBu = (const u16*)(ws + OFF_WBB);

    for (int i = tid; i < 2048; i += 256) {
      const int row = i >> 4, e0 = (i & 15) * 4;
      const float4 v = *(const float4*)(x + (base + row) * 64 + e0);
      u16* dst = &XAu[row * 72 + e0];
      dst[0] = f2bf(v.x); dst[1] = f2bf(v.y); dst[2] = f2bf(v.z); dst[3] = f2bf(v.w);
    }
    __syncthreads();

    floatx4 acc[2][4] = {};
#pragma unroll
    for (int kc = 0; kc < 2; ++kc) {
      short8 af[2];
#pragma unroll
      for (int mi = 0; mi < 2; ++mi)
        af[mi] = *(const short8*)&XAu[(32 * wv + 16 * mi + lc) * 72 + kc * 32 + quad * 8];
#pragma unroll
      for (int ni = 0; ni < 4; ++ni) {
        const short8 bf_ = *(const short8*)&WBBu[(ni * 16 + lc) * 64 + kc * 32 + quad * 8];
#pragma unroll
        for (int mi = 0; mi < 2; ++mi)
          acc[mi][ni] = __builtin_amdgcn_mfma_f32_16x16x32_bf16(af[mi], bf_, acc[mi][ni], 0, 0, 0);
      }
    }
    __syncthreads();   // all XA reads complete before xcT overwrite

    u16* xcT = XAu;    // [64 d][132]
#pragma unroll
    for (int ni = 0; ni < 4; ++ni)
#pragma unroll
      for (int mi = 0; mi < 2; ++mi)
#pragma unroll
        for (int reg = 0; reg < 4; ++reg)
          xcT[(ni * 16 + lc) * 132 + 32 * wv + 16 * mi + quad * 4 + reg] =
              f2bf(acc[mi][ni][reg]);
    __syncthreads();
    u16* XCT = (u16*)(ws + OFF_XCT);
    for (int i = tid; i < 8192; i += 256) {
      const int d = i >> 7, r = i & 127;
      const unsigned int row = (unsigned int)(base + r);
      const unsigned int bt = row / 325u;
      const unsigned int n = row - bt * 325u;
      XCT[(size_t)bt * 22528 + (size_t)d * 352 + n] = xcT[d * 132 + r];
    }
  } else if (blk < 2009) {
    // ================= xa: alternating sums of x =================
    const int idx = (blk - 1359) * 256 + tid;
    if (idx >= 32 * 325 * 16) return;
    const int dq = idx & 15;            // float4 slot
    const int n = (idx >> 4) % 325;
    const int b = idx / (16 * 325);
    const float* xp = x + ((size_t)b * 3900 + (size_t)n * 12) * 64 + dq * 4;
    float4 s = make_float4(0.f, 0.f, 0.f, 0.f);
    float sign = 1.f;
    for (int k = 0; k < 12; ++k) {
      const float4 v = *(const float4*)(xp + (size_t)k * 64);
      s.x += sign * v.x; s.y += sign * v.y; s.z += sign * v.z; s.w += sign * v.w;
      sign = -sign;
    }
    *(float4*)(ws + OFF_XA + ((size_t)b * 325 + n) * 64 + dq * 4) = s;
  } else if (blk < 2334) {
    // ================= ANB: adj row-normalize -> bf16 (final2-only) =================
    const int n = blk - 2009;           // < 325
    float* red = smem;
    float p = 0.f;
    for (int k = tid; k < 325; k += 256) p += adj[n * 325 + k];
    red[tid] = p;
    __syncthreads();
    for (int s2 = 128; s2 > 0; s2 >>= 1) {
      if (tid < s2) red[tid] += red[tid + s2];
      __syncthreads();
    }
    const float inv = 1.f / red[0];
    u16* ANB = (u16*)(ws + OFF_ANB);
    for (int k = tid; k < 352; k += 256)
      ANB[(size_t)n * 352 + k] = (k < 325) ? f2bf(adj[n * 325 + k] * inv) : (u16)0;
  } else if (blk < 2430) {
    // ================= XCT n-pad zeroing (final2-only) =================
    const int idx = (blk - 2334) * 256 + tid;   // < 24576 = 384*64
    u16* p = (u16*)(ws + OFF_XCT) + (size_t)(idx >> 6) * 22528 + (size_t)(idx & 63) * 352;
    for (int c = 325; c < 352; ++c) p[c] = 0;
  } else {
    // ================= WVTB (final2-only) =================
    u16* WVTBu = (u16*)(ws + OFF_WVTB);
    for (int i = tid; i < 4096; i += 256) WVTBu[i] = f2bf(Wvt[i]);
  }
}

// =======  K3: barrier-free MFMA — C = AN@XCT + T2@OFT + TE@Wvt + bias  =======
// XCD-swizzled blockIdx: the 3 mc-blocks of one bt share its XCT panel on one XCD L2.
__global__ __launch_bounds__(256) void k_final2(const float* __restrict__ x,
                                                const float* __restrict__ bmlp,
                                                float* __restrict__ ws,
                                                float* __restrict__ out) {
  const int tid = threadIdx.x;
  const int wg = (blockIdx.x & 7) * 144 + (blockIdx.x >> 3);   // 1152 = 8 x 144
  const int bt = wg / 3, mc = wg % 3;
  const int m0 = mc * 128;
  const int wave = tid >> 6, lane = tid & 63;
  const int quad = lane >> 4, lc = lane & 15;

  const u16* ANB = (const u16*)(ws + OFF_ANB);
  const u16* T2B = (const u16*)(ws + OFF_T2);
  const u16* XCT = (const u16*)(ws + OFF_XCT) + (size_t)bt * 22528;
  const u16* OFT = (const u16*)(ws + OFF_OFT) + (size_t)bt * 4096;
  const u16* WVTBu = (const u16*)(ws + OFF_WVTB);

  const int b = bt / 12, t = bt - b * 12;
  const float sgn12 = ((t & 1) ? -1.f : 1.f) * (1.f / 12.f);

  floatx4 acc[2][4] = {};

#pragma unroll
  for (int c13 = 0; c13 < 13; ++c13) {
    const bool gcn = (c13 < 11);
    const u16* Asrc = gcn ? ANB : T2B;
    const int astr = gcn ? 352 : 64;
    const int acol = gcn ? c13 * 32 : (c13 - 11) * 32;
    const u16* Bsrc = gcn ? XCT : OFT;
    const int bstr = gcn ? 352 : 64;
    short8 af[2], bf_[4];
#pragma unroll
    for (int mi = 0; mi < 2; ++mi) {
      const int gr = m0 + wave * 32 + mi * 16 + lc;
      short8 a = {};
      if (gr < 325)
        a = *(const short8*)&Asrc[(size_t)gr * astr + acol + quad * 8];
      af[mi] = a;
    }
#pragma unroll
    for (int ni = 0; ni < 4; ++ni)
      bf_[ni] = *(const short8*)&Bsrc[(size_t)(ni * 16 + lc) * bstr + acol + quad * 8];
#pragma unroll
    for (int mi = 0; mi < 2; ++mi)
#pragma unroll
      for (int ni = 0; ni < 4; ++ni)
        acc[mi][ni] = __builtin_amdgcn_mfma_f32_16x16x32_bf16(
            af[mi], bf_[ni], acc[mi][ni], 0, 0, 0);
  }

  // --- te GEMM: A' = (x_row(n*12+t) - sgn*xa_n/12)/6, B = Wvt ---
#pragma unroll
  for (int kc = 0; kc < 2; ++kc) {
    const int k0 = kc * 32 + quad * 8;
    short8 af[2];
#pragma unroll
    for (int mi = 0; mi < 2; ++mi) {
      const int nr = m0 + wave * 32 + mi * 16 + lc;
      short8 a = {};
      if (nr < 325) {
        const float* xp = x + ((size_t)b * 3900 + (size_t)nr * 12 + t) * 64 + k0;
        const float* xap = ws + OFF_XA + ((size_t)b * 325 + nr) * 64 + k0;
        float xv[8], av[8];
        *(float4*)xv = *(const float4*)xp;
        *(float4*)(xv + 4) = *(const float4*)(xp + 4);
        *(float4*)av = *(const float4*)xap;
        *(float4*)(av + 4) = *(const float4*)(xap + 4);
#pragma unroll
        for (int u = 0; u < 8; ++u)
          a[u] = (short)f2bf((xv[u] - sgn12 * av[u]) * (1.f / 6.f));
      }
      af[mi] = a;
    }
#pragma unroll
    for (int ni = 0; ni < 4; ++ni) {
      const short8 bf_ = *(const short8*)&WVTBu[(size_t)(ni * 16 + lc) * 64 + k0];
#pragma unroll
      for (int mi = 0; mi < 2; ++mi)
        acc[mi][ni] = __builtin_amdgcn_mfma_f32_16x16x32_bf16(
            af[mi], bf_, acc[mi][ni], 0, 0, 0);
    }
  }

#pragma unroll
  for (int ni = 0; ni < 4; ++ni) {
    const int d = ni * 16 + lc;
    const float bias = bmlp[d];
#pragma unroll
    for (int mi = 0; mi < 2; ++mi) {
#pragma unroll
      for (int reg = 0; reg < 4; ++reg) {
        const int n = m0 + wave * 32 + mi * 16 + quad * 4 + reg;
        if (n >= 325) continue;
        out[((size_t)bt * 325 + n) * 64 + d] = acc[mi][ni][reg] + bias;
      }
    }
  }
}

extern "C" void kernel_launch(void* const* d_in, const int* in_sizes, int n_in,
                              void* d_out, int out_size, void* d_ws, size_t ws_size,
                              hipStream_t stream) {
  const float* x = (const float*)d_in[0];
  const float* adj = (const float*)d_in[1];
  const float* Wq_g = (const float*)d_in[2];
  const float* Wk_g = (const float*)d_in[3];
  const float* Wv_g = (const float*)d_in[4];
  // d_in[5], d_in[6] (Wq_t, Wk_t), d_in[12] (weights_Q_t), d_in[14] (t_modes):
  // dead code — temporal softmax axis == mean axis => out = vf/6.
  const float* Wv_t = (const float*)d_in[7];
  const float* Wfc1 = (const float*)d_in[8];
  const float* Wmlp = (const float*)d_in[9];
  const float* bmlp = (const float*)d_in[10];
  const float* wQ = (const float*)d_in[11];
  const int* sp_modes = (const int*)d_in[13];
  float* ws = (float*)d_ws;
  float* out = (float*)d_out;

  (void)in_sizes; (void)n_in; (void)out_size; (void)ws_size;

  k_prep0<<<2, 256, 0, stream>>>(Wq_g, Wk_g, ws);
  k_prep<<<997, 256, 0, stream>>>(x, Wmlp, Wfc1, wQ, Wq_g, Wk_g, Wv_g,
                                  sp_modes, ws);
  k_mega<<<2431, 256, 0, stream>>>(x, adj, Wv_t, ws);
  k_final2<<<1152, 256, 0, stream>>>(x, bmlp, ws, out);
}